// Round 1
// baseline (120.583 us; speedup 1.0000x reference)
//
#include <hip/hip_runtime.h>

// Problem constants
#define HDIM 512
#define NVAR 32
#define LAGD 1024
#define BATCH 256
#define MDIM 1024

typedef __attribute__((ext_vector_type(4))) float f32x4;
typedef __attribute__((ext_vector_type(8))) short short8;
typedef __attribute__((ext_vector_type(4))) unsigned short us4;
typedef __attribute__((ext_vector_type(8))) unsigned short us8;

__device__ __forceinline__ unsigned short f2bf(float f) {
  union { float f; unsigned u; } x; x.f = f;
  unsigned r = x.u + 0x7fffu + ((x.u >> 16) & 1u);  // RNE
  return (unsigned short)(r >> 16);
}
__device__ __forceinline__ float bf2f(unsigned short s) {
  union { unsigned u; float f; } x; x.u = ((unsigned)s) << 16;
  return x.f;
}

// ---------------------------------------------------------------------------
// K1: per-variable gates GEMM.  C[v][m][n] = sum_k X[m][v][k] * Wsel[v][n][k]
//   n in [0,512)  -> W_ih row n        (i gate)
//   n in [512,1024)-> W_ih row n+512   (g gate, orig rows 1024..1535)
// 128x128 tile, BK=32, 4 waves, mfma_f32_16x16x32_bf16, fp32->bf16 in staging.
// ---------------------------------------------------------------------------
__global__ __launch_bounds__(256) void k1_gates(
    const float* __restrict__ X,     // [BATCH][NVAR][LAGD]
    const float* __restrict__ W,     // [NVAR][4*HDIM][LAGD]
    float* __restrict__ gates)       // [NVAR][BATCH][1024]
{
  const int v  = blockIdx.z;
  const int m0 = blockIdx.y * 128;
  const int n0 = blockIdx.x * 128;
  const int tid  = threadIdx.x;
  const int lane = tid & 63;
  const int wv   = tid >> 6;
  const int wr   = wv >> 1, wc = wv & 1;

  __shared__ unsigned short As[128][40];  // +8 pad: 2-way banks only
  __shared__ unsigned short Bs[128][40];

  f32x4 acc[4][4] = {};

  const int trow = tid >> 3;        // 0..31
  const int tcol = (tid & 7) << 2;  // 0,4,...,28

  const float* Xbase = X + (size_t)v * LAGD;
  const float* Wbase = W + (size_t)v * (4 * HDIM) * LAGD;

  for (int k0 = 0; k0 < LAGD; k0 += 32) {
    // stage A (X tile): 128 rows x 32 k, fp32 -> bf16
#pragma unroll
    for (int p = 0; p < 4; ++p) {
      int r = (p << 5) + trow;
      f32x4 d = *(const f32x4*)(Xbase + (size_t)(m0 + r) * (NVAR * LAGD) + k0 + tcol);
      us4 u; u[0] = f2bf(d[0]); u[1] = f2bf(d[1]); u[2] = f2bf(d[2]); u[3] = f2bf(d[3]);
      *(us4*)&As[r][tcol] = u;
    }
    // stage B (W rows, i/g-selected)
#pragma unroll
    for (int p = 0; p < 4; ++p) {
      int r = (p << 5) + trow;
      int ng = n0 + r;
      int rs = ng + ((ng >= 512) ? 512 : 0);
      f32x4 d = *(const f32x4*)(Wbase + (size_t)rs * LAGD + k0 + tcol);
      us4 u; u[0] = f2bf(d[0]); u[1] = f2bf(d[1]); u[2] = f2bf(d[2]); u[3] = f2bf(d[3]);
      *(us4*)&Bs[r][tcol] = u;
    }
    __syncthreads();

    const int koff = (lane >> 4) << 3;
    const int fr   = lane & 15;
    short8 a[4], b[4];
#pragma unroll
    for (int i = 0; i < 4; ++i)
      a[i] = *(const short8*)&As[(wr << 6) + (i << 4) + fr][koff];
#pragma unroll
    for (int i = 0; i < 4; ++i)
      b[i] = *(const short8*)&Bs[(wc << 6) + (i << 4) + fr][koff];
#pragma unroll
    for (int i = 0; i < 4; ++i)
#pragma unroll
      for (int j = 0; j < 4; ++j)
        acc[i][j] = __builtin_amdgcn_mfma_f32_16x16x32_bf16(a[i], b[j], acc[i][j], 0, 0, 0);
    __syncthreads();
  }

  // store C tile: D layout col=lane&15, row=(lane>>4)*4+r  [m89-verified]
  const int col  = lane & 15;
  const int row4 = (lane >> 4) << 2;
  float* outp = gates + ((size_t)v * BATCH + m0) * 1024 + n0;
#pragma unroll
  for (int i = 0; i < 4; ++i)
#pragma unroll
    for (int j = 0; j < 4; ++j)
#pragma unroll
      for (int r = 0; r < 4; ++r)
        outp[(size_t)((wr << 6) + (i << 4) + row4 + r) * 1024 + (wc << 6) + (j << 4) + col]
            = acc[i][j][r];
}

// ---------------------------------------------------------------------------
// K2: activation epilogue.  agg[b][v*512+h] = bf16( sigmoid(i)*tanh(g)*imp[v] )
// ---------------------------------------------------------------------------
__global__ __launch_bounds__(256) void k2_act(
    const float* __restrict__ gates,  // [NVAR][BATCH][1024]
    const float* __restrict__ b_ih,   // [NVAR][4*HDIM]
    const float* __restrict__ b_hh,
    const float* __restrict__ imp,    // [NVAR]
    unsigned short* __restrict__ agg) // [BATCH][NVAR*HDIM] bf16
{
  const size_t idx = (size_t)blockIdx.x * 256 + threadIdx.x;  // B*V*H
  const int h = (int)(idx & 511);
  const int v = (int)((idx >> 9) & 31);
  const int b = (int)(idx >> 14);
  const size_t base = ((size_t)v * BATCH + b) * 1024;
  float ig = gates[base + h];
  float gg = gates[base + 512 + h];
  ig += b_ih[v * 2048 + h] + b_hh[v * 2048 + h];
  gg += b_ih[v * 2048 + 1024 + h] + b_hh[v * 2048 + 1024 + h];
  float sig = 1.0f / (1.0f + __expf(-ig));
  float c = sig * tanhf(gg);
  agg[idx] = f2bf(c * imp[v]);
}

// ---------------------------------------------------------------------------
// K3: mlp1 split-K GEMM.  part[s][m][n] = sum_{k in split s} agg[m][k]*W1[n][k]
// split s = variable v (K slice of 512).  A already bf16; B fp32->bf16.
// ---------------------------------------------------------------------------
__global__ __launch_bounds__(256) void k3_mlp1(
    const unsigned short* __restrict__ A,  // agg [BATCH][16384] bf16
    const float* __restrict__ Wm,          // [1024][16384] fp32
    float* __restrict__ part)              // [32][BATCH][1024]
{
  const int s  = blockIdx.z;
  const int m0 = blockIdx.y * 128;
  const int n0 = blockIdx.x * 128;
  const int tid  = threadIdx.x;
  const int lane = tid & 63;
  const int wv   = tid >> 6;
  const int wr   = wv >> 1, wc = wv & 1;

  __shared__ unsigned short As[128][40];
  __shared__ unsigned short Bs[128][40];

  f32x4 acc[4][4] = {};

  const int trowA = tid >> 2;        // 0..63
  const int tcolA = (tid & 3) << 3;  // 0,8,16,24
  const int trow  = tid >> 3;
  const int tcol  = (tid & 7) << 2;

  const unsigned short* Abase = A + (size_t)s * 512;
  const float* Wbase = Wm + (size_t)s * 512;

  for (int k0 = 0; k0 < 512; k0 += 32) {
#pragma unroll
    for (int p = 0; p < 2; ++p) {
      int r = (p << 6) + trowA;
      us8 d = *(const us8*)(Abase + (size_t)(m0 + r) * 16384 + k0 + tcolA);
      *(us8*)&As[r][tcolA] = d;
    }
#pragma unroll
    for (int p = 0; p < 4; ++p) {
      int r = (p << 5) + trow;
      f32x4 d = *(const f32x4*)(Wbase + (size_t)(n0 + r) * 16384 + k0 + tcol);
      us4 u; u[0] = f2bf(d[0]); u[1] = f2bf(d[1]); u[2] = f2bf(d[2]); u[3] = f2bf(d[3]);
      *(us4*)&Bs[r][tcol] = u;
    }
    __syncthreads();

    const int koff = (lane >> 4) << 3;
    const int fr   = lane & 15;
    short8 a[4], b[4];
#pragma unroll
    for (int i = 0; i < 4; ++i)
      a[i] = *(const short8*)&As[(wr << 6) + (i << 4) + fr][koff];
#pragma unroll
    for (int i = 0; i < 4; ++i)
      b[i] = *(const short8*)&Bs[(wc << 6) + (i << 4) + fr][koff];
#pragma unroll
    for (int i = 0; i < 4; ++i)
#pragma unroll
      for (int j = 0; j < 4; ++j)
        acc[i][j] = __builtin_amdgcn_mfma_f32_16x16x32_bf16(a[i], b[j], acc[i][j], 0, 0, 0);
    __syncthreads();
  }

  const int col  = lane & 15;
  const int row4 = (lane >> 4) << 2;
  float* outp = part + ((size_t)s * BATCH + m0) * 1024 + n0;
#pragma unroll
  for (int i = 0; i < 4; ++i)
#pragma unroll
    for (int j = 0; j < 4; ++j)
#pragma unroll
      for (int r = 0; r < 4; ++r)
        outp[(size_t)((wr << 6) + (i << 4) + row4 + r) * 1024 + (wc << 6) + (j << 4) + col]
            = acc[i][j][r];
}

// ---------------------------------------------------------------------------
// K4: reduce split-K partials + bias + relu -> hid bf16 [BATCH][1024]
// ---------------------------------------------------------------------------
__global__ __launch_bounds__(256) void k4_reduce(
    const float* __restrict__ part,   // [32][BATCH][1024]
    const float* __restrict__ b1,     // [1024]
    unsigned short* __restrict__ hid) // [BATCH][1024] bf16
{
  const int idx = blockIdx.x * 256 + threadIdx.x;  // BATCH*1024
  const int n = idx & 1023;
  const int b = idx >> 10;
  float s = b1[n];
#pragma unroll 8
  for (int t = 0; t < 32; ++t)
    s += part[((size_t)t * BATCH + b) * 1024 + n];
  s = fmaxf(s, 0.0f);
  hid[idx] = f2bf(s);
}

// ---------------------------------------------------------------------------
// K5: mlp2.  out[b] = b2 + sum_n hid[b][n]*w2[n].  One wave per row.
// ---------------------------------------------------------------------------
__global__ __launch_bounds__(256) void k5_mlp2(
    const unsigned short* __restrict__ hid,  // [BATCH][1024] bf16
    const float* __restrict__ w2,            // [1024]
    const float* __restrict__ b2,            // [1]
    float* __restrict__ out)                 // [BATCH]
{
  const int b    = blockIdx.x * 4 + (threadIdx.x >> 6);
  const int lane = threadIdx.x & 63;
  float s = 0.0f;
#pragma unroll
  for (int n = lane; n < 1024; n += 64)
    s += bf2f(hid[b * 1024 + n]) * w2[n];
#pragma unroll
  for (int off = 32; off > 0; off >>= 1)
    s += __shfl_down(s, off);
  if (lane == 0) out[b] = s + b2[0];
}

// ---------------------------------------------------------------------------
extern "C" void kernel_launch(void* const* d_in, const int* in_sizes, int n_in,
                              void* d_out, int out_size, void* d_ws, size_t ws_size,
                              hipStream_t stream) {
  const float* inputs = (const float*)d_in[0];
  const float* W_ih   = (const float*)d_in[1];
  // d_in[2] = W_hh: unused (h0 == 0)
  const float* b_ih   = (const float*)d_in[3];
  const float* b_hh   = (const float*)d_in[4];
  const float* imp    = (const float*)d_in[5];
  const float* m1w    = (const float*)d_in[6];
  const float* m1b    = (const float*)d_in[7];
  const float* m2w    = (const float*)d_in[8];
  const float* m2b    = (const float*)d_in[9];
  float* out = (float*)d_out;

  char* ws = (char*)d_ws;
  unsigned short* agg = (unsigned short*)ws;                // 8 MB  [256][16384] bf16
  float* gates        = (float*)(ws + (8u << 20));          // 32 MB [32][256][1024] f32
  float* part         = gates;                              // reused after K2
  unsigned short* hid = (unsigned short*)(ws + (40u << 20));// 0.5 MB [256][1024] bf16

  k1_gates<<<dim3(8, 2, 32), 256, 0, stream>>>(inputs, W_ih, gates);
  k2_act  <<<dim3(16384),    256, 0, stream>>>(gates, b_ih, b_hh, imp, agg);
  k3_mlp1 <<<dim3(8, 2, 32), 256, 0, stream>>>(agg, m1w, part);
  k4_reduce<<<dim3(1024),    256, 0, stream>>>(part, m1b, hid);
  k5_mlp2 <<<dim3(64),       256, 0, stream>>>(hid, m2w, m2b, out);
}